// Round 3
// baseline (406.805 us; speedup 1.0000x reference)
//
#include <hip/hip_runtime.h>
#include <stdint.h>

typedef unsigned short u16;
typedef unsigned int u32;
typedef __attribute__((ext_vector_type(4))) float f32x4;
typedef __attribute__((ext_vector_type(8))) __bf16 bf16x8;

#define EPS_BN 1e-5f

__device__ __forceinline__ u16 f2bf(float f) {
  u32 u = __builtin_bit_cast(u32, f);
  u32 r = (u + 0x7fffu + ((u >> 16) & 1u)) >> 16;
  return (u16)r;
}

__device__ __forceinline__ float silu_f(float v) {
  return v / (1.0f + __expf(-v));
}

// async global->LDS, 16B per lane; dest = wave-uniform base + lane*16
__device__ __forceinline__ void gll16(const void* g, void* l) {
  __builtin_amdgcn_global_load_lds(
      (__attribute__((address_space(1))) void*)(void*)g,
      (__attribute__((address_space(3))) void*)l, 16, 0, 0);
}

// ---------------------------------------------------------------------------
// prep: pack weights (bf16, block-diagonal qkv + hid, channel-major), BN fold,
// zero page. Wt[j][k], j in [0,512), k = tap*256 + c, tap = kh*3+kw.
// ---------------------------------------------------------------------------
__global__ __launch_bounds__(256) void prep(
    const float* __restrict__ qkv_w, const float* __restrict__ qg,
    const float* __restrict__ qb, const float* __restrict__ qm,
    const float* __restrict__ qv,
    const float* __restrict__ hid_w, const float* __restrict__ hg,
    const float* __restrict__ hb, const float* __restrict__ hm,
    const float* __restrict__ hv,
    const float* __restrict__ out_w, const float* __restrict__ og,
    const float* __restrict__ ob, const float* __restrict__ om,
    const float* __restrict__ ov,
    u16* __restrict__ wtb, u16* __restrict__ w2b,
    float* __restrict__ bn1s, float* __restrict__ bn1b,
    float* __restrict__ bn2s, float* __restrict__ bn2b,
    float* __restrict__ zpg)
{
  const int gid = blockIdx.x * 256 + threadIdx.x;
  if (gid < 512 * 2304) {
    int j = gid / 2304, k = gid - j * 2304;
    int tap = k >> 8, cch = k & 255;
    float v = 0.f;
    if (j < 160) {
      int g = j / 20;              // group of 20 output channels
      int cg = cch - g * 32;       // input channel within group
      if ((unsigned)cg < 32u) v = qkv_w[(j * 32 + cg) * 9 + tap];
    } else if (j < 416) {
      v = hid_w[((j - 160) * 256 + cch) * 9 + tap];
    }
    wtb[(size_t)j * 2304 + k] = f2bf(v);
  }
  if (gid < 98304) w2b[gid] = f2bf(out_w[gid]);   // [256][384]
  if (gid < 512) {
    float sc = 0.f, bi = 0.f;
    if (gid < 160) {
      float iv = qg[gid] * rsqrtf(qv[gid] + EPS_BN);
      sc = iv; bi = qb[gid] - qm[gid] * iv;
    } else if (gid < 416) {
      int c = gid - 160;
      float iv = hg[c] * rsqrtf(hv[c] + EPS_BN);
      sc = iv; bi = hb[c] - hm[c] * iv;
    }
    bn1s[gid] = sc; bn1b[gid] = bi;
  }
  if (gid < 256) {
    float iv = og[gid] * rsqrtf(ov[gid] + EPS_BN);
    bn2s[gid] = iv; bn2b[gid] = ob[gid] - om[gid] * iv;
  }
  if (gid < 64) zpg[gid] = 0.f;
}

// ---------------------------------------------------------------------------
// NCHW fp32 -> NHWC bf16 (one (b,h,ctile-of-64) per block, padded LDS)
// ---------------------------------------------------------------------------
__global__ __launch_bounds__(256) void nchw2nhwc(
    const float* __restrict__ x, u16* __restrict__ xn)
{
  __shared__ u16 T[80 * 66];       // [w][c] pad 66 -> conflict-free both phases
  const int t = threadIdx.x;
  const int ct = blockIdx.x;       // 0..3
  const int h  = blockIdx.y;       // 0..79
  const int b  = blockIdx.z;       // 0..15
  const float* src = x + ((size_t)b * 256 + ct * 64) * 6400 + h * 80;
  for (int it = 0; it < 20; ++it) {
    int idx = it * 256 + t;        // 0..5119
    int cl = idx / 80, wl = idx - cl * 80;
    T[wl * 66 + cl] = f2bf(src[(size_t)cl * 6400 + wl]);
  }
  __syncthreads();
  u16* dst = xn + ((size_t)(b * 80 + h) * 80) * 256 + ct * 64;
  for (int it = 0; it < 5; ++it) {
    int idx = it * 256 + t;        // 0..1279
    int wl = idx >> 4;
    int cl = (idx & 15) * 4;
    ushort4 v4;
    v4.x = T[wl * 66 + cl + 0];
    v4.y = T[wl * 66 + cl + 1];
    v4.z = T[wl * 66 + cl + 2];
    v4.w = T[wl * 66 + cl + 3];
    *(ushort4*)(dst + (size_t)wl * 256 + cl) = v4;
  }
}

// ---------------------------------------------------------------------------
// Main GEMM: C[pixel][chan] = im2col(x_nhwc) @ Wt^T, 128x128 tile, BK=64.
// LDS layout for both tiles: [row 0..127][8 chunks of 8 bf16], chunk slot s at
// row m holds source chunk s^(m&7)  (XOR swizzle, applied source-side so
// global_load_lds' linear dest works; read side applies the same XOR).
// Epilogue: BN+SiLU; j<160 -> qkv fp32, 160<=j<416 -> Ycat bf16 col j-32.
// ---------------------------------------------------------------------------
__global__ __launch_bounds__(256, 2) void gemm_main(
    const u16* __restrict__ xn, const u16* __restrict__ wt,
    const float* __restrict__ bns, const float* __restrict__ bnb,
    const float* __restrict__ zpg,
    float* __restrict__ qkvb, u16* __restrict__ ycat)
{
  __shared__ __attribute__((aligned(16))) u16 Al[128 * 64];
  __shared__ __attribute__((aligned(16))) u16 Bl[128 * 64];
  const int t = threadIdx.x;
  const int wave = t >> 6, lane = t & 63;
  const int wr = wave >> 1, wc = wave & 1;
  const int jtile = blockIdx.x * 128;   // channel tile 0..3
  const int ptile = blockIdx.y * 128;   // pixel tile 0..799 (never crosses b)

  const int srcc = (((lane & 7) ^ ((lane >> 3) & 7)) * 8); // swizzled src chunk
  int pb[4], hh[4], wwv[4], bofB[4];
#pragma unroll
  for (int c = 0; c < 4; ++c) {
    int m = wave * 32 + c * 8 + (lane >> 3);
    int p = ptile + m;
    pb[c] = p;
    int hw = p % 6400;
    hh[c] = hw / 80;
    wwv[c] = hw - (hw / 80) * 80;
    bofB[c] = (jtile + m) * 2304 + srcc;
  }
  u16* AlW = Al + wave * 2048;   // 32 rows * 64
  u16* BlW = Bl + wave * 2048;

  f32x4 acc[4][4];
#pragma unroll
  for (int m = 0; m < 4; ++m)
#pragma unroll
    for (int n = 0; n < 4; ++n) {
      f32x4 z = {0.f, 0.f, 0.f, 0.f};
      acc[m][n] = z;
    }

  for (int ks = 0; ks < 36; ++ks) {
    const int k0 = ks * 64;
    const int tap = k0 >> 8;
    const int c0 = k0 & 255;
    const int dh = tap / 3 - 1, dw = tap - (tap / 3) * 3 - 1;
    __syncthreads();
#pragma unroll
    for (int c = 0; c < 4; ++c) {
      int h2 = hh[c] + dh, w2 = wwv[c] + dw;
      bool ok = ((unsigned)h2 < 80u) & ((unsigned)w2 < 80u);
      const u16* src = ok
          ? (xn + ((size_t)(pb[c] + dh * 80 + dw) * 256 + c0 + srcc))
          : (const u16*)zpg;
      gll16(src, AlW + c * 512);
    }
#pragma unroll
    for (int c = 0; c < 4; ++c)
      gll16(wt + (size_t)(bofB[c] + k0), BlW + c * 512);
    __syncthreads();
#pragma unroll
    for (int kk = 0; kk < 2; ++kk) {
      const int q = kk * 4 + (lane >> 4);
      const int c16 = lane & 15;
      bf16x8 av[4], bv[4];
#pragma unroll
      for (int m = 0; m < 4; ++m) {
        int r = wr * 64 + m * 16 + c16;
        av[m] = *(const bf16x8*)(Al + r * 64 + (q ^ (r & 7)) * 8);
      }
#pragma unroll
      for (int n = 0; n < 4; ++n) {
        int r = wc * 64 + n * 16 + c16;
        bv[n] = *(const bf16x8*)(Bl + r * 64 + (q ^ (r & 7)) * 8);
      }
#pragma unroll
      for (int m = 0; m < 4; ++m)
#pragma unroll
        for (int n = 0; n < 4; ++n)
          acc[m][n] = __builtin_amdgcn_mfma_f32_16x16x32_bf16(
              av[m], bv[n], acc[m][n], 0, 0, 0);
    }
  }

  const int c16 = lane & 15, rg = lane >> 4;
#pragma unroll
  for (int n = 0; n < 4; ++n) {
    int j = jtile + wc * 64 + n * 16 + c16;
    if (j >= 416) continue;
    float sc = bns[j], bi = bnb[j];
#pragma unroll
    for (int m = 0; m < 4; ++m) {
      int p0 = ptile + wr * 64 + m * 16 + rg * 4;
#pragma unroll
      for (int r = 0; r < 4; ++r) {
        float v = silu_f(acc[m][n][r] * sc + bi);
        int p = p0 + r;
        if (j < 160) qkvb[(size_t)p * 160 + j] = v;
        else ycat[(size_t)p * 384 + (j - 32)] = f2bf(v);
      }
    }
  }
}

// ---------------------------------------------------------------------------
// Attention: per pixel 16x16 softmax(q_i*k_j) @ v[j][d]; thread = (pixel, i).
// ---------------------------------------------------------------------------
__global__ __launch_bounds__(256) void attn_k(
    const float* __restrict__ qkvb, u16* __restrict__ ycat)
{
  __shared__ float qs[16 * 168];   // stride 168 (mod-32-banks = 8) kills conflicts
  const int t = threadIdx.x;
  const size_t p0 = (size_t)blockIdx.x * 16;
  const float* src = qkvb + p0 * 160;
  for (int idx = t; idx < 2560; idx += 256) {
    int r = idx / 160;
    qs[r * 168 + (idx - r * 160)] = src[idx];
  }
  __syncthreads();
  const int px = t >> 4, i = t & 15;
  const float* row = qs + px * 168;
  const float qi = row[i];
  float s[16];
  float mx = -3.4e38f;
#pragma unroll
  for (int j = 0; j < 16; ++j) { s[j] = qi * row[16 + j]; mx = fmaxf(mx, s[j]); }
  float sum = 0.f;
#pragma unroll
  for (int j = 0; j < 16; ++j) { s[j] = __expf(s[j] - mx); sum += s[j]; }
  const float inv = 1.0f / sum;
  float y[8];
#pragma unroll
  for (int d = 0; d < 8; ++d) y[d] = 0.f;
#pragma unroll
  for (int j = 0; j < 16; ++j) {
    const float a = s[j];
    const float* vr = row + 32 + j * 8;
#pragma unroll
    for (int d = 0; d < 8; ++d) y[d] += a * vr[d];
  }
  union { u16 u[8]; uint4 v4; } pk;
#pragma unroll
  for (int d = 0; d < 8; ++d) pk.u[d] = f2bf(y[d] * inv);
  *(uint4*)(ycat + (p0 + px) * 384 + i * 8) = pk.v4;
}

// ---------------------------------------------------------------------------
// Output GEMM: out[oc][p] = SiLU(BN(W2[oc][:] . Ycat[p][:])). A=W2 (rows=oc),
// B=Ycat (rows=pixels) so C col = pixel -> coalesced NCHW fp32 stores.
// ---------------------------------------------------------------------------
__global__ __launch_bounds__(256, 2) void gemm_out(
    const u16* __restrict__ w2, const u16* __restrict__ ycat,
    const float* __restrict__ bns, const float* __restrict__ bnb,
    float* __restrict__ out)
{
  __shared__ __attribute__((aligned(16))) u16 Al[128 * 64];
  __shared__ __attribute__((aligned(16))) u16 Bl[128 * 64];
  const int t = threadIdx.x;
  const int wave = t >> 6, lane = t & 63;
  const int wr = wave >> 1, wc = wave & 1;
  const int octile = blockIdx.x * 128;
  const int ptile = blockIdx.y * 128;

  const int srcc = (((lane & 7) ^ ((lane >> 3) & 7)) * 8);
  int bofA[4], bofB[4];
#pragma unroll
  for (int c = 0; c < 4; ++c) {
    int m = wave * 32 + c * 8 + (lane >> 3);
    bofA[c] = (octile + m) * 384 + srcc;
    bofB[c] = (ptile + m) * 384 + srcc;
  }
  u16* AlW = Al + wave * 2048;
  u16* BlW = Bl + wave * 2048;

  f32x4 acc[4][4];
#pragma unroll
  for (int m = 0; m < 4; ++m)
#pragma unroll
    for (int n = 0; n < 4; ++n) {
      f32x4 z = {0.f, 0.f, 0.f, 0.f};
      acc[m][n] = z;
    }

  for (int ks = 0; ks < 6; ++ks) {
    const int k0 = ks * 64;
    __syncthreads();
#pragma unroll
    for (int c = 0; c < 4; ++c) gll16(w2 + (size_t)(bofA[c] + k0), AlW + c * 512);
#pragma unroll
    for (int c = 0; c < 4; ++c) gll16(ycat + (size_t)(bofB[c] + k0), BlW + c * 512);
    __syncthreads();
#pragma unroll
    for (int kk = 0; kk < 2; ++kk) {
      const int q = kk * 4 + (lane >> 4);
      const int c16 = lane & 15;
      bf16x8 av[4], bv[4];
#pragma unroll
      for (int m = 0; m < 4; ++m) {
        int r = wr * 64 + m * 16 + c16;
        av[m] = *(const bf16x8*)(Al + r * 64 + (q ^ (r & 7)) * 8);
      }
#pragma unroll
      for (int n = 0; n < 4; ++n) {
        int r = wc * 64 + n * 16 + c16;
        bv[n] = *(const bf16x8*)(Bl + r * 64 + (q ^ (r & 7)) * 8);
      }
#pragma unroll
      for (int m = 0; m < 4; ++m)
#pragma unroll
        for (int n = 0; n < 4; ++n)
          acc[m][n] = __builtin_amdgcn_mfma_f32_16x16x32_bf16(
              av[m], bv[n], acc[m][n], 0, 0, 0);
    }
  }

  const int c16 = lane & 15, rg = lane >> 4;
  const int b = ptile / 6400;
  const int hwb = ptile - b * 6400;
#pragma unroll
  for (int m = 0; m < 4; ++m) {
    int oc0 = octile + wr * 64 + m * 16 + rg * 4;
#pragma unroll
    for (int n = 0; n < 4; ++n) {
      int hw = hwb + wc * 64 + n * 16 + c16;
#pragma unroll
      for (int r = 0; r < 4; ++r) {
        int oc = oc0 + r;
        float v = silu_f(acc[m][n][r] * bns[oc] + bnb[oc]);
        out[((size_t)b * 256 + oc) * 6400 + hw] = v;
      }
    }
  }
}

// ---------------------------------------------------------------------------
// ws layout (bytes):
//   0        zero page (256)
//   256      bn1 scale (512*4)      2304   bn1 bias (512*4)
//   4352     bn2 scale (256*4)      5376   bn2 bias (256*4)
//   6400     Wt  [512][2304] bf16   (2,359,296)
//   2365696  W2  [256][384]  bf16   (196,608)
//   2562304  x_nhwc [102400][256] bf16 (52,428,800)
//   54991104 qkv [102400][160] fp32 (65,536,000)
//   120527104 Ycat [102400][384] bf16 (78,643,200)  -> total 199,170,304 B
// ---------------------------------------------------------------------------
extern "C" void kernel_launch(void* const* d_in, const int* in_sizes, int n_in,
                              void* d_out, int out_size, void* d_ws, size_t ws_size,
                              hipStream_t stream) {
  (void)in_sizes; (void)n_in; (void)out_size; (void)ws_size;
  const float* x    = (const float*)d_in[0];
  const float* qkvw = (const float*)d_in[1];
  const float* qg   = (const float*)d_in[2];
  const float* qb   = (const float*)d_in[3];
  const float* qm   = (const float*)d_in[4];
  const float* qv   = (const float*)d_in[5];
  const float* hw_  = (const float*)d_in[6];
  const float* hg   = (const float*)d_in[7];
  const float* hb   = (const float*)d_in[8];
  const float* hm   = (const float*)d_in[9];
  const float* hv   = (const float*)d_in[10];
  const float* ow   = (const float*)d_in[11];
  const float* og   = (const float*)d_in[12];
  const float* ob   = (const float*)d_in[13];
  const float* om   = (const float*)d_in[14];
  const float* ov   = (const float*)d_in[15];

  char* ws = (char*)d_ws;
  float* zpg  = (float*)(ws + 0);
  float* bn1s = (float*)(ws + 256);
  float* bn1b = (float*)(ws + 2304);
  float* bn2s = (float*)(ws + 4352);
  float* bn2b = (float*)(ws + 5376);
  u16*   wtb  = (u16*)(ws + 6400);
  u16*   w2b  = (u16*)(ws + 2365696);
  u16*   xn   = (u16*)(ws + 2562304);
  float* qkvb = (float*)(ws + 54991104);
  u16*   ycat = (u16*)(ws + 120527104);
  float* out  = (float*)d_out;

  prep<<<dim3(4608), dim3(256), 0, stream>>>(
      qkvw, qg, qb, qm, qv, hw_, hg, hb, hm, hv, ow, og, ob, om, ov,
      wtb, w2b, bn1s, bn1b, bn2s, bn2b, zpg);
  nchw2nhwc<<<dim3(4, 80, 16), dim3(256), 0, stream>>>(x, xn);
  gemm_main<<<dim3(4, 800), dim3(256), 0, stream>>>(
      xn, wtb, bn1s, bn1b, zpg, qkvb, ycat);
  attn_k<<<dim3(6400), dim3(256), 0, stream>>>(qkvb, ycat);
  gemm_out<<<dim3(2, 800), dim3(256), 0, stream>>>(
      w2b, ycat, bn2s, bn2b, out);
}

// Round 4
// 356.018 us; speedup vs baseline: 1.1427x; 1.1427x over previous
//
#include <hip/hip_runtime.h>
#include <stdint.h>

typedef unsigned short u16;
typedef unsigned int u32;
typedef __attribute__((ext_vector_type(4))) float f32x4;
typedef __attribute__((ext_vector_type(8))) __bf16 bf16x8;

#define EPS_BN 1e-5f

__device__ __forceinline__ u16 f2bf(float f) {
  u32 u = __builtin_bit_cast(u32, f);
  u32 r = (u + 0x7fffu + ((u >> 16) & 1u)) >> 16;
  return (u16)r;
}

__device__ __forceinline__ float silu_f(float v) {
  return v / (1.0f + __expf(-v));
}

// async global->LDS, 16B per lane; dest = wave-uniform base + lane*16
__device__ __forceinline__ void gll16(const void* g, void* l) {
  __builtin_amdgcn_global_load_lds(
      (__attribute__((address_space(1))) void*)(void*)g,
      (__attribute__((address_space(3))) void*)l, 16, 0, 0);
}

// ---------------------------------------------------------------------------
// prep: hid weights channel-major bf16 [256][2304] (k = tap*256 + c),
// qkv grouped weights [8][32pad][288] (k = tap*32 + cg), out weights bf16,
// BN folds, zero page.
// ---------------------------------------------------------------------------
__global__ __launch_bounds__(256) void prep(
    const float* __restrict__ qkv_w, const float* __restrict__ qg,
    const float* __restrict__ qb, const float* __restrict__ qm,
    const float* __restrict__ qv,
    const float* __restrict__ hid_w, const float* __restrict__ hg,
    const float* __restrict__ hb, const float* __restrict__ hm,
    const float* __restrict__ hv,
    const float* __restrict__ out_w, const float* __restrict__ og,
    const float* __restrict__ ob, const float* __restrict__ om,
    const float* __restrict__ ov,
    u16* __restrict__ wtb, u16* __restrict__ w2b, u16* __restrict__ wqp,
    float* __restrict__ bnq_s, float* __restrict__ bnq_b,
    float* __restrict__ bnh_s, float* __restrict__ bnh_b,
    float* __restrict__ bn2s, float* __restrict__ bn2b,
    float* __restrict__ zpg)
{
  const int gid = blockIdx.x * 256 + threadIdx.x;
  if (gid < 256 * 2304) {            // hid weights, channel-major
    int j = gid / 2304, k = gid - j * 2304;
    int tap = k >> 8, c = k & 255;
    wtb[gid] = f2bf(hid_w[(j * 256 + c) * 9 + tap]);
  }
  if (gid < 73728) {                 // qkv grouped weights [g][j<32][288]
    int g = gid / 9216;
    int r = gid - g * 9216;
    int j = r / 288, k = r - j * 288;
    int tap = k >> 5, cg = k & 31;
    float v = 0.f;
    if (j < 20) v = qkv_w[((g * 20 + j) * 32 + cg) * 9 + tap];
    wqp[gid] = f2bf(v);
  }
  if (gid < 98304) w2b[gid] = f2bf(out_w[gid]);   // [256][384]
  if (gid < 160) {
    float iv = qg[gid] * rsqrtf(qv[gid] + EPS_BN);
    bnq_s[gid] = iv; bnq_b[gid] = qb[gid] - qm[gid] * iv;
  }
  if (gid < 256) {
    float iv = hg[gid] * rsqrtf(hv[gid] + EPS_BN);
    bnh_s[gid] = iv; bnh_b[gid] = hb[gid] - hm[gid] * iv;
    float iv2 = og[gid] * rsqrtf(ov[gid] + EPS_BN);
    bn2s[gid] = iv2; bn2b[gid] = ob[gid] - om[gid] * iv2;
  }
  if (gid < 64) zpg[gid] = 0.f;
}

// ---------------------------------------------------------------------------
// NCHW fp32 -> NHWC bf16 (one (b,h,ctile-of-64) per block, padded LDS)
// ---------------------------------------------------------------------------
__global__ __launch_bounds__(256) void nchw2nhwc(
    const float* __restrict__ x, u16* __restrict__ xn)
{
  __shared__ u16 T[80 * 66];
  const int t = threadIdx.x;
  const int ct = blockIdx.x;       // 0..3
  const int h  = blockIdx.y;       // 0..79
  const int b  = blockIdx.z;       // 0..15
  const float* src = x + ((size_t)b * 256 + ct * 64) * 6400 + h * 80;
  for (int it = 0; it < 20; ++it) {
    int idx = it * 256 + t;
    int cl = idx / 80, wl = idx - cl * 80;
    T[wl * 66 + cl] = f2bf(src[(size_t)cl * 6400 + wl]);
  }
  __syncthreads();
  u16* dst = xn + ((size_t)(b * 80 + h) * 80) * 256 + ct * 64;
  for (int it = 0; it < 5; ++it) {
    int idx = it * 256 + t;
    int wl = idx >> 4;
    int cl = (idx & 15) * 4;
    ushort4 v4;
    v4.x = T[wl * 66 + cl + 0];
    v4.y = T[wl * 66 + cl + 1];
    v4.z = T[wl * 66 + cl + 2];
    v4.w = T[wl * 66 + cl + 3];
    *(ushort4*)(dst + (size_t)wl * 256 + cl) = v4;
  }
}

// ---------------------------------------------------------------------------
// hid GEMM: Ycat[p][128+j] = SiLU(BN(im2col(xn) @ Wh^T)), 128x128 tile, BK=64.
// XOR-swizzled LDS (source-side pre-swizzle + swizzled ds_read, rule #21).
// XCD-aware block swizzle: each XCD gets 1 jtile x 200 contiguous ptiles.
// ---------------------------------------------------------------------------
__global__ __launch_bounds__(256, 2) void gemm_main(
    const u16* __restrict__ xn, const u16* __restrict__ wt,
    const float* __restrict__ bns, const float* __restrict__ bnb,
    const float* __restrict__ zpg, u16* __restrict__ ycat)
{
  __shared__ __attribute__((aligned(16))) u16 Al[128 * 64];
  __shared__ __attribute__((aligned(16))) u16 Bl[128 * 64];
  const int t = threadIdx.x;
  const int wave = t >> 6, lane = t & 63;
  const int wr = wave >> 1, wc = wave & 1;
  // bijective XCD swizzle: nwg = 1600 = 8*200
  const int orig = blockIdx.y * 2 + blockIdx.x;
  const int wg = (orig & 7) * 200 + (orig >> 3);
  const int jtile = (wg / 800) * 128;
  const int ptile = (wg % 800) * 128;

  const int srcc = (((lane & 7) ^ ((lane >> 3) & 7)) * 8); // swizzled src chunk
  int pb[4], hh[4], wwv[4], bofB[4];
#pragma unroll
  for (int c = 0; c < 4; ++c) {
    int m = wave * 32 + c * 8 + (lane >> 3);
    int p = ptile + m;
    pb[c] = p;
    int hw = p % 6400;
    hh[c] = hw / 80;
    wwv[c] = hw - (hw / 80) * 80;
    bofB[c] = (jtile + m) * 2304 + srcc;
  }
  u16* AlW = Al + wave * 2048;
  u16* BlW = Bl + wave * 2048;

  f32x4 acc[4][4];
#pragma unroll
  for (int m = 0; m < 4; ++m)
#pragma unroll
    for (int n = 0; n < 4; ++n) {
      f32x4 z = {0.f, 0.f, 0.f, 0.f};
      acc[m][n] = z;
    }

  for (int ks = 0; ks < 36; ++ks) {
    const int k0 = ks * 64;
    const int tap = k0 >> 8;
    const int c0 = k0 & 255;
    const int dh = tap / 3 - 1, dw = tap - (tap / 3) * 3 - 1;
    __syncthreads();
#pragma unroll
    for (int c = 0; c < 4; ++c) {
      int h2 = hh[c] + dh, w2 = wwv[c] + dw;
      bool ok = ((unsigned)h2 < 80u) & ((unsigned)w2 < 80u);
      const u16* src = ok
          ? (xn + ((size_t)(pb[c] + dh * 80 + dw) * 256 + c0 + srcc))
          : (const u16*)zpg;
      gll16(src, AlW + c * 512);
    }
#pragma unroll
    for (int c = 0; c < 4; ++c)
      gll16(wt + (size_t)(bofB[c] + k0), BlW + c * 512);
    __syncthreads();
#pragma unroll
    for (int kk = 0; kk < 2; ++kk) {
      const int q = kk * 4 + (lane >> 4);
      const int c16 = lane & 15;
      bf16x8 av[4], bv[4];
#pragma unroll
      for (int m = 0; m < 4; ++m) {
        int r = wr * 64 + m * 16 + c16;
        av[m] = *(const bf16x8*)(Al + r * 64 + (q ^ (r & 7)) * 8);
      }
#pragma unroll
      for (int n = 0; n < 4; ++n) {
        int r = wc * 64 + n * 16 + c16;
        bv[n] = *(const bf16x8*)(Bl + r * 64 + (q ^ (r & 7)) * 8);
      }
#pragma unroll
      for (int m = 0; m < 4; ++m)
#pragma unroll
        for (int n = 0; n < 4; ++n)
          acc[m][n] = __builtin_amdgcn_mfma_f32_16x16x32_bf16(
              av[m], bv[n], acc[m][n], 0, 0, 0);
    }
  }

  const int c16 = lane & 15, rg = lane >> 4;
#pragma unroll
  for (int n = 0; n < 4; ++n) {
    int j = jtile + wc * 64 + n * 16 + c16;   // 0..255
    float sc = bns[j], bi = bnb[j];
#pragma unroll
    for (int m = 0; m < 4; ++m) {
      int p0 = ptile + wr * 64 + m * 16 + rg * 4;
#pragma unroll
      for (int r = 0; r < 4; ++r) {
        float v = silu_f(acc[m][n][r] * sc + bi);
        ycat[(size_t)(p0 + r) * 384 + 128 + j] = f2bf(v);
      }
    }
  }
}

// ---------------------------------------------------------------------------
// qkv grouped conv as GEMM: block = (256 pixels, group g), K=288, N=20->32.
// B staged once in LDS (stride 296 for bank spread); A frags loaded straight
// from global to registers (per-lane halo select to zero; xn is L2-hot).
// ---------------------------------------------------------------------------
__global__ __launch_bounds__(256) void qkv_gemm(
    const u16* __restrict__ xn, const u16* __restrict__ wqp,
    const float* __restrict__ bnq_s, const float* __restrict__ bnq_b,
    float* __restrict__ qkvb)
{
  __shared__ __attribute__((aligned(16))) u16 Bs[32 * 296];
  const int t = threadIdx.x;
  const int wave = t >> 6, lane = t & 63;
  const int g = blockIdx.y;
  const int pt0 = blockIdx.x * 256;

  for (int idx = t; idx < 9216; idx += 256) {
    int j = idx / 288, k = idx - j * 288;
    Bs[j * 296 + k] = wqp[(size_t)(g * 32 + j) * 288 + k];
  }
  __syncthreads();

  const int c16 = lane & 15, q = lane >> 4;
  int pix[4], ph[4], pw[4];
#pragma unroll
  for (int m = 0; m < 4; ++m) {
    pix[m] = pt0 + wave * 64 + m * 16 + c16;
    int hw = pix[m] % 6400;
    ph[m] = hw / 80;
    pw[m] = hw - (hw / 80) * 80;
  }
  f32x4 acc[4][2];
#pragma unroll
  for (int m = 0; m < 4; ++m)
#pragma unroll
    for (int n = 0; n < 2; ++n) {
      f32x4 z = {0.f, 0.f, 0.f, 0.f};
      acc[m][n] = z;
    }
  bf16x8 zv;
#pragma unroll
  for (int i = 0; i < 8; ++i) zv[i] = (__bf16)0.0f;

#pragma unroll
  for (int tap = 0; tap < 9; ++tap) {
    const int dh = tap / 3 - 1, dw = tap - (tap / 3) * 3 - 1;
    const int dp = dh * 80 + dw;
    const bf16x8 bv0 = *(const bf16x8*)(Bs + c16 * 296 + tap * 32 + q * 8);
    const bf16x8 bv1 = *(const bf16x8*)(Bs + (16 + c16) * 296 + tap * 32 + q * 8);
#pragma unroll
    for (int m = 0; m < 4; ++m) {
      bool ok = ((unsigned)(ph[m] + dh) < 80u) & ((unsigned)(pw[m] + dw) < 80u);
      // always-safe load: offset stays within d_ws even at the halo edges
      const bf16x8 raw = *(const bf16x8*)(
          xn + (long)(pix[m] + dp) * 256 + g * 32 + q * 8);
      const bf16x8 av = ok ? raw : zv;
      acc[m][0] = __builtin_amdgcn_mfma_f32_16x16x32_bf16(av, bv0, acc[m][0], 0, 0, 0);
      acc[m][1] = __builtin_amdgcn_mfma_f32_16x16x32_bf16(av, bv1, acc[m][1], 0, 0, 0);
    }
  }

#pragma unroll
  for (int n = 0; n < 2; ++n) {
    int jj = n * 16 + c16;
    if (jj < 20) {
      int oc = g * 20 + jj;
      float sc = bnq_s[oc], bi = bnq_b[oc];
#pragma unroll
      for (int m = 0; m < 4; ++m) {
        int p0 = pt0 + wave * 64 + m * 16 + q * 4;
#pragma unroll
        for (int r = 0; r < 4; ++r)
          qkvb[(size_t)(p0 + r) * 160 + oc] = silu_f(acc[m][n][r] * sc + bi);
      }
    }
  }
}

// ---------------------------------------------------------------------------
// Attention: per pixel 16x16 softmax(q_i*k_j) @ v[j][d]; thread = (pixel, i).
// ---------------------------------------------------------------------------
__global__ __launch_bounds__(256) void attn_k(
    const float* __restrict__ qkvb, u16* __restrict__ ycat)
{
  __shared__ float qs[16 * 168];
  const int t = threadIdx.x;
  const size_t p0 = (size_t)blockIdx.x * 16;
  const float* src = qkvb + p0 * 160;
  for (int idx = t; idx < 2560; idx += 256) {
    int r = idx / 160;
    qs[r * 168 + (idx - r * 160)] = src[idx];
  }
  __syncthreads();
  const int px = t >> 4, i = t & 15;
  const float* row = qs + px * 168;
  const float qi = row[i];
  float s[16];
  float mx = -3.4e38f;
#pragma unroll
  for (int j = 0; j < 16; ++j) { s[j] = qi * row[16 + j]; mx = fmaxf(mx, s[j]); }
  float sum = 0.f;
#pragma unroll
  for (int j = 0; j < 16; ++j) { s[j] = __expf(s[j] - mx); sum += s[j]; }
  const float inv = 1.0f / sum;
  float y[8];
#pragma unroll
  for (int d = 0; d < 8; ++d) y[d] = 0.f;
#pragma unroll
  for (int j = 0; j < 16; ++j) {
    const float a = s[j];
    const float* vr = row + 32 + j * 8;
#pragma unroll
    for (int d = 0; d < 8; ++d) y[d] += a * vr[d];
  }
  union { u16 u[8]; uint4 v4; } pk;
#pragma unroll
  for (int d = 0; d < 8; ++d) pk.u[d] = f2bf(y[d] * inv);
  *(uint4*)(ycat + (p0 + px) * 384 + i * 8) = pk.v4;
}

// ---------------------------------------------------------------------------
// Output GEMM: out[oc][p] = SiLU(BN(W2[oc][:] . Ycat[p][:])). A=W2 rows=oc,
// B=Ycat rows=pixels -> C col = pixel -> coalesced NCHW fp32 stores.
// ---------------------------------------------------------------------------
__global__ __launch_bounds__(256, 2) void gemm_out(
    const u16* __restrict__ w2, const u16* __restrict__ ycat,
    const float* __restrict__ bns, const float* __restrict__ bnb,
    float* __restrict__ out)
{
  __shared__ __attribute__((aligned(16))) u16 Al[128 * 64];
  __shared__ __attribute__((aligned(16))) u16 Bl[128 * 64];
  const int t = threadIdx.x;
  const int wave = t >> 6, lane = t & 63;
  const int wr = wave >> 1, wc = wave & 1;
  const int orig = blockIdx.y * 2 + blockIdx.x;
  const int wg = (orig & 7) * 200 + (orig >> 3);
  const int octile = (wg / 800) * 128;
  const int ptile = (wg % 800) * 128;

  const int srcc = (((lane & 7) ^ ((lane >> 3) & 7)) * 8);
  int bofA[4], bofB[4];
#pragma unroll
  for (int c = 0; c < 4; ++c) {
    int m = wave * 32 + c * 8 + (lane >> 3);
    bofA[c] = (octile + m) * 384 + srcc;
    bofB[c] = (ptile + m) * 384 + srcc;
  }
  u16* AlW = Al + wave * 2048;
  u16* BlW = Bl + wave * 2048;

  f32x4 acc[4][4];
#pragma unroll
  for (int m = 0; m < 4; ++m)
#pragma unroll
    for (int n = 0; n < 4; ++n) {
      f32x4 z = {0.f, 0.f, 0.f, 0.f};
      acc[m][n] = z;
    }

  for (int ks = 0; ks < 6; ++ks) {
    const int k0 = ks * 64;
    __syncthreads();
#pragma unroll
    for (int c = 0; c < 4; ++c) gll16(w2 + (size_t)(bofA[c] + k0), AlW + c * 512);
#pragma unroll
    for (int c = 0; c < 4; ++c) gll16(ycat + (size_t)(bofB[c] + k0), BlW + c * 512);
    __syncthreads();
#pragma unroll
    for (int kk = 0; kk < 2; ++kk) {
      const int q = kk * 4 + (lane >> 4);
      const int c16 = lane & 15;
      bf16x8 av[4], bv[4];
#pragma unroll
      for (int m = 0; m < 4; ++m) {
        int r = wr * 64 + m * 16 + c16;
        av[m] = *(const bf16x8*)(Al + r * 64 + (q ^ (r & 7)) * 8);
      }
#pragma unroll
      for (int n = 0; n < 4; ++n) {
        int r = wc * 64 + n * 16 + c16;
        bv[n] = *(const bf16x8*)(Bl + r * 64 + (q ^ (r & 7)) * 8);
      }
#pragma unroll
      for (int m = 0; m < 4; ++m)
#pragma unroll
        for (int n = 0; n < 4; ++n)
          acc[m][n] = __builtin_amdgcn_mfma_f32_16x16x32_bf16(
              av[m], bv[n], acc[m][n], 0, 0, 0);
    }
  }

  const int c16 = lane & 15, rg = lane >> 4;
  const int b = ptile / 6400;
  const int hwb = ptile - b * 6400;
#pragma unroll
  for (int m = 0; m < 4; ++m) {
    int oc0 = octile + wr * 64 + m * 16 + rg * 4;
#pragma unroll
    for (int n = 0; n < 4; ++n) {
      int hw = hwb + wc * 64 + n * 16 + c16;
#pragma unroll
      for (int r = 0; r < 4; ++r) {
        int oc = oc0 + r;
        float v = silu_f(acc[m][n][r] * bns[oc] + bnb[oc]);
        out[((size_t)b * 256 + oc) * 6400 + hw] = v;
      }
    }
  }
}

// ---------------------------------------------------------------------------
// ws layout (bytes):
//   0        zero page (256)
//   256      bnq_s(640) 1280 bnq_b(640) 2304 bnh_s(1024) 3328 bnh_b(1024)
//   4352     bn2s(1024) 5376 bn2b(1024)
//   6400     wtb  [256][2304] bf16 (1,179,648)
//   1186048  w2b  [256][384]  bf16 (196,608)
//   1382656  wqp  [8][32][288] bf16 (147,456)
//   1536000  x_nhwc [102400][256] bf16 (52,428,800)
//   53964800 qkv [102400][160] fp32 (65,536,000)
//   119500800 Ycat [102400][384] bf16 (78,643,200) -> total 198,144,000 B
// ---------------------------------------------------------------------------
extern "C" void kernel_launch(void* const* d_in, const int* in_sizes, int n_in,
                              void* d_out, int out_size, void* d_ws, size_t ws_size,
                              hipStream_t stream) {
  (void)in_sizes; (void)n_in; (void)out_size; (void)ws_size;
  const float* x    = (const float*)d_in[0];
  const float* qkvw = (const float*)d_in[1];
  const float* qg   = (const float*)d_in[2];
  const float* qb   = (const float*)d_in[3];
  const float* qm   = (const float*)d_in[4];
  const float* qv   = (const float*)d_in[5];
  const float* hw_  = (const float*)d_in[6];
  const float* hg   = (const float*)d_in[7];
  const float* hb   = (const float*)d_in[8];
  const float* hm   = (const float*)d_in[9];
  const float* hv   = (const float*)d_in[10];
  const float* ow   = (const float*)d_in[11];
  const float* og   = (const float*)d_in[12];
  const float* ob   = (const float*)d_in[13];
  const float* om   = (const float*)d_in[14];
  const float* ov   = (const float*)d_in[15];

  char* ws = (char*)d_ws;
  float* zpg   = (float*)(ws + 0);
  float* bnq_s = (float*)(ws + 256);
  float* bnq_b = (float*)(ws + 1280);
  float* bnh_s = (float*)(ws + 2304);
  float* bnh_b = (float*)(ws + 3328);
  float* bn2s  = (float*)(ws + 4352);
  float* bn2b  = (float*)(ws + 5376);
  u16*   wtb   = (u16*)(ws + 6400);
  u16*   w2b   = (u16*)(ws + 1186048);
  u16*   wqp   = (u16*)(ws + 1382656);
  u16*   xn    = (u16*)(ws + 1536000);
  float* qkvb  = (float*)(ws + 53964800);
  u16*   ycat  = (u16*)(ws + 119500800);
  float* out   = (float*)d_out;

  prep<<<dim3(2304), dim3(256), 0, stream>>>(
      qkvw, qg, qb, qm, qv, hw_, hg, hb, hm, hv, ow, og, ob, om, ov,
      wtb, w2b, wqp, bnq_s, bnq_b, bnh_s, bnh_b, bn2s, bn2b, zpg);
  nchw2nhwc<<<dim3(4, 80, 16), dim3(256), 0, stream>>>(x, xn);
  gemm_main<<<dim3(2, 800), dim3(256), 0, stream>>>(
      xn, wtb, bnh_s, bnh_b, zpg, ycat);
  qkv_gemm<<<dim3(400, 8), dim3(256), 0, stream>>>(
      xn, wqp, bnq_s, bnq_b, qkvb);
  attn_k<<<dim3(6400), dim3(256), 0, stream>>>(qkvb, ycat);
  gemm_out<<<dim3(2, 800), dim3(256), 0, stream>>>(
      w2b, ycat, bn2s, bn2b, out);
}